// Round 1
// 1950.736 us; speedup vs baseline: 1.4345x; 1.4345x over previous
//
#include <hip/hip_runtime.h>
#include <math.h>

// Problem constants: B=8, N=1024, C=768, H=12, hd=64
#define Bb 8
#define Nn 1024
#define Cc 768
#define Hh 12
#define HD 64
#define LD 2304   // qkv buffer leading dim (3*C)

typedef __attribute__((ext_vector_type(4))) float f32x4;
typedef __attribute__((ext_vector_type(8))) short bf16x8;

// ---------------------------------------------------------------------------
// fp32 -> bf16 (round-nearest-even) and back
__device__ __forceinline__ unsigned short f2bf(float x) {
    unsigned u = __float_as_uint(x);
    return (unsigned short)((u + 0x7FFFu + ((u >> 16) & 1u)) >> 16);
}
__device__ __forceinline__ float bf2f(unsigned short h) {
    return __uint_as_float(((unsigned)h) << 16);
}
__device__ __forceinline__ void split4(float4 v, ushort4& h, ushort4& l) {
    h.x = f2bf(v.x); l.x = f2bf(v.x - bf2f(h.x));
    h.y = f2bf(v.y); l.y = f2bf(v.y - bf2f(h.y));
    h.z = f2bf(v.z); l.z = f2bf(v.z - bf2f(h.z));
    h.w = f2bf(v.w); l.w = f2bf(v.w - bf2f(h.w));
}

// ---------------------------------------------------------------------------
// Split-bf16 MFMA GEMM (fp32-equivalent precision via hi/lo 3-term products).
// BT==0:  C = alpha * (A @ B^T)   A:[M,K] ld=lda, B:[N,K] ld=ldb
// BT==1:  C = alpha * (A @ B)     A:[M,K] ld=lda, B:[K,N] ld=ldb
// optional: accum (C +=), bias[col], add[row,col]
// grid = (M/BM, N/BN, batches); batch z -> b1=z/zdiv, b2=z%zdiv.
// Requires M%BM==0, N%BN==0, K%32==0, all row strides multiples of 4 floats.
template<int BM, int BN, int BT>
__global__ __launch_bounds__(256)
void gemm_mfma(const float* __restrict__ A, int lda, long sA1, long sA2,
               const float* __restrict__ B, int ldb, long sB1, long sB2,
               float* __restrict__ C, int ldc, long sC1, long sC2,
               const float* __restrict__ add, const float* __restrict__ bias,
               int K, int zdiv, float alpha, int accum)
{
    constexpr int KS = 32;          // fp32 k-elements per step (== MFMA K in bf16)
    constexpr int LK = KS + 8;      // padded LDS leading dim (bf16 elems): 80B rows
    constexpr int FM = BM / 64;     // 16x16 frags per wave in M (wave owns BM/4 rows)
    constexpr int FN = BN / 16;     // frags in N (wave owns all columns)

    __shared__ short Ah[BM * LK];
    __shared__ short Al[BM * LK];
    __shared__ short Bh[BN * LK];
    __shared__ short Bl[BN * LK];

    int z = blockIdx.z;
    int b1 = z / zdiv, b2 = z - b1 * zdiv;
    A += (long)b1 * sA1 + (long)b2 * sA2;
    B += (long)b1 * sB1 + (long)b2 * sB2;
    long coff = (long)b1 * sC1 + (long)b2 * sC2;
    C += coff;
    if (add) add += coff;

    int m0 = blockIdx.x * BM;
    int n0 = blockIdx.y * BN;
    int tid = threadIdx.x;
    int lane = tid & 63, wid = tid >> 6;
    int wrow = wid * (BM / 4);
    int lr = lane & 15;        // frag row (A) / col (B)
    int lk = lane >> 4;        // k-group: 8 contiguous bf16 at lk*8

    f32x4 acc[FM][FN] = {};

    for (int k0 = 0; k0 < K; k0 += KS) {
        // ---- stage A tile [BM][32] fp32 -> hi/lo bf16 LDS ----
#pragma unroll
        for (int idx = tid; idx < BM * 8; idx += 256) {
            int row = idx >> 3, kq = idx & 7;
            float4 v = *(const float4*)&A[(long)(m0 + row) * lda + (k0 + kq * 4)];
            ushort4 h, l; split4(v, h, l);
            *(ushort4*)&Ah[row * LK + kq * 4] = h;
            *(ushort4*)&Al[row * LK + kq * 4] = l;
        }
        // ---- stage B tile -> [BN][32] hi/lo bf16 LDS ----
        if (BT == 0) {
#pragma unroll
            for (int idx = tid; idx < BN * 8; idx += 256) {
                int row = idx >> 3, kq = idx & 7;
                float4 v = *(const float4*)&B[(long)(n0 + row) * ldb + (k0 + kq * 4)];
                ushort4 h, l; split4(v, h, l);
                *(ushort4*)&Bh[row * LK + kq * 4] = h;
                *(ushort4*)&Bl[row * LK + kq * 4] = l;
            }
        } else {
            constexpr int NQ = BN / 4;   // float4s per k-row
#pragma unroll
            for (int idx = tid; idx < KS * NQ; idx += 256) {
                int kk = idx / NQ, nq = idx - (idx / NQ) * NQ;
                float4 v = *(const float4*)&B[(long)(k0 + kk) * ldb + (n0 + nq * 4)];
                ushort4 h, l; split4(v, h, l);
                int r0 = nq * 4;
                Bh[(r0 + 0) * LK + kk] = h.x; Bl[(r0 + 0) * LK + kk] = l.x;
                Bh[(r0 + 1) * LK + kk] = h.y; Bl[(r0 + 1) * LK + kk] = l.y;
                Bh[(r0 + 2) * LK + kk] = h.z; Bl[(r0 + 2) * LK + kk] = l.z;
                Bh[(r0 + 3) * LK + kk] = h.w; Bl[(r0 + 3) * LK + kk] = l.w;
            }
        }
        __syncthreads();

        // ---- MFMA: acc += Ah*Bh + Al*Bh + Ah*Bl ----
        bf16x8 ahf[FM], alf[FM];
#pragma unroll
        for (int fm = 0; fm < FM; ++fm) {
            int row = wrow + fm * 16 + lr;
            ahf[fm] = *(const bf16x8*)&Ah[row * LK + lk * 8];
            alf[fm] = *(const bf16x8*)&Al[row * LK + lk * 8];
        }
#pragma unroll
        for (int fn = 0; fn < FN; ++fn) {
            int col = fn * 16 + lr;
            bf16x8 bh = *(const bf16x8*)&Bh[col * LK + lk * 8];
            bf16x8 bl = *(const bf16x8*)&Bl[col * LK + lk * 8];
#pragma unroll
            for (int fm = 0; fm < FM; ++fm) {
                acc[fm][fn] = __builtin_amdgcn_mfma_f32_16x16x32_bf16(ahf[fm], bh, acc[fm][fn], 0, 0, 0);
                acc[fm][fn] = __builtin_amdgcn_mfma_f32_16x16x32_bf16(alf[fm], bh, acc[fm][fn], 0, 0, 0);
                acc[fm][fn] = __builtin_amdgcn_mfma_f32_16x16x32_bf16(ahf[fm], bl, acc[fm][fn], 0, 0, 0);
            }
        }
        __syncthreads();
    }

    // ---- epilogue: C/D layout is col=lane&15, row=(lane>>4)*4+reg ----
#pragma unroll
    for (int fm = 0; fm < FM; ++fm) {
#pragma unroll
        for (int fn = 0; fn < FN; ++fn) {
            int col = n0 + fn * 16 + lr;
            float bv = bias ? bias[col] : 0.0f;
#pragma unroll
            for (int r = 0; r < 4; ++r) {
                int row = m0 + wrow + fm * 16 + lk * 4 + r;
                long idx = (long)row * ldc + col;
                float v = alpha * acc[fm][fn][r];
                if (accum) v += C[idx];
                v += bv;
                if (add) v += add[idx];
                C[idx] = v;
            }
        }
    }
}

// ---------------------------------------------------------------------------
__device__ inline float waveReduceSum(float v) {
#pragma unroll
    for (int off = 32; off; off >>= 1) v += __shfl_down(v, off, 64);
    return v;
}
__device__ inline float waveReduceMax(float v) {
#pragma unroll
    for (int off = 32; off; off >>= 1) v = fmaxf(v, __shfl_down(v, off, 64));
    return v;
}

// in-place row softmax, one block per row of 1024
__global__ __launch_bounds__(256)
void softmax_rows(float* __restrict__ p)
{
    long row = blockIdx.x;
    float* r = p + row * 1024;
    int tid = threadIdx.x;
    float4 x = ((float4*)r)[tid];
    float m = fmaxf(fmaxf(x.x, x.y), fmaxf(x.z, x.w));
    m = waveReduceMax(m);
    __shared__ float sm[4];
    __shared__ float bm, bs;
    int lane = tid & 63, wid = tid >> 6;
    if (!lane) sm[wid] = m;
    __syncthreads();
    if (tid == 0) bm = fmaxf(fmaxf(sm[0], sm[1]), fmaxf(sm[2], sm[3]));
    __syncthreads();
    float mm = bm;
    x.x = expf(x.x - mm); x.y = expf(x.y - mm);
    x.z = expf(x.z - mm); x.w = expf(x.w - mm);
    float s = x.x + x.y + x.z + x.w;
    s = waveReduceSum(s);
    if (!lane) sm[wid] = s;
    __syncthreads();
    if (tid == 0) bs = sm[0] + sm[1] + sm[2] + sm[3];
    __syncthreads();
    float inv = 1.0f / bs;
    x.x *= inv; x.y *= inv; x.z *= inv; x.w *= inv;
    ((float4*)r)[tid] = x;
}

// AH[b,i,j] = relu((AH[b,i,j]+AH[b,j,i])/2), in-place, pair-symmetric
__global__ __launch_bounds__(256)
void sym_relu(float* __restrict__ AH)
{
    long idx = (long)blockIdx.x * 256 + threadIdx.x;
    if (idx >= (long)Bb * Nn * Nn) return;
    int b = (int)(idx >> 20);
    int r = (int)(idx & 1048575);
    int i = r >> 10, j = r & 1023;
    if (j < i) return;
    float* Ab = AH + ((long)b << 20);
    float t = 0.5f * (Ab[i * 1024 + j] + Ab[j * 1024 + i]);
    t = fmaxf(t, 0.0f);
    Ab[i * 1024 + j] = t;
    Ab[j * 1024 + i] = t;
}

// dinv[b,i] = deg!=0 ? rsqrt(deg) : 0 ; deg = row sum of AH
__global__ __launch_bounds__(256)
void deg_dinv(const float* __restrict__ AH, float* __restrict__ dinv)
{
    long row = blockIdx.x;                 // 0..8191  (b*1024+i)
    const float* r = AH + row * 1024;
    int tid = threadIdx.x;
    float4 x = ((const float4*)r)[tid];
    float s = x.x + x.y + x.z + x.w;
    s = waveReduceSum(s);
    __shared__ float sm[4];
    int lane = tid & 63, wid = tid >> 6;
    if (!lane) sm[wid] = s;
    __syncthreads();
    if (tid == 0) {
        float d = sm[0] + sm[1] + sm[2] + sm[3];
        dinv[row] = (d != 0.0f) ? rsqrtf(d) : 0.0f;
    }
}

// AH[b,i,j] *= dinv[b,i]*dinv[b,j]
__global__ __launch_bounds__(256)
void scale_ah(float* __restrict__ AH, const float* __restrict__ dinv)
{
    long idx = (long)blockIdx.x * 256 + threadIdx.x;
    if (idx >= (long)Bb * Nn * Nn) return;
    int b = (int)(idx >> 20);
    int i = (int)((idx >> 10) & 1023);
    int j = (int)(idx & 1023);
    AH[idx] *= dinv[(b << 10) + i] * dinv[(b << 10) + j];
}

// circulant taps of the rfft*w->irfft gate (ortho norm, numpy c2r semantics)
__global__ void build_g(const float* __restrict__ cw, float* __restrict__ g)
{
    int d = threadIdx.x;
    if (d >= 64) return;
    float s = cw[0] + ((d & 1) ? -cw[64] : cw[64]);
#pragma unroll
    for (int f = 1; f < 32; ++f) {
        int ph = (f * d) & 63;
        float ang = 6.283185307179586f * (float)ph / 64.0f;
        s += 2.0f * (cw[2 * f] * cosf(ang) + cw[2 * f + 1] * sinf(ang));
    }
    g[d] = s * 0.015625f;   // 1/64
}

// wdiff = w_v1 - w_v2
__global__ __launch_bounds__(256)
void wdiff_k(const float* __restrict__ a, const float* __restrict__ b,
             float* __restrict__ o)
{
    int i = blockIdx.x * 256 + threadIdx.x;
    if (i < Cc * Cc) o[i] = a[i] - b[i];
}

// ifv[b,n,h*64+t] = sum_m V[b,n,h*64+m] * g[(m-t)&63], one block per (b,n)
__global__ __launch_bounds__(256)
void ifv_kernel(const float* __restrict__ qkv, const float* __restrict__ g,
                float* __restrict__ ifv)
{
    int bn = blockIdx.x;   // 0..8191
    __shared__ float Vr[768];
    __shared__ float Gs[64];
    const float* vrow = qkv + (long)bn * LD + 2 * Cc;   // V slice
    int tid = threadIdx.x;
    if (tid < 64) Gs[tid] = g[tid];
    for (int c = tid; c < 768; c += 256) Vr[c] = vrow[c];
    __syncthreads();
    for (int c = tid; c < 768; c += 256) {
        int h = c >> 6, t = c & 63;
        const float* vh = Vr + (h << 6);
        float s = 0.0f;
#pragma unroll
        for (int m2 = 0; m2 < 64; ++m2)
            s = fmaf(vh[m2], Gs[(m2 - t) & 63], s);
        ifv[(long)bn * 768 + c] = s;
    }
}

// ---------------------------------------------------------------------------
extern "C" void kernel_launch(void* const* d_in, const int* in_sizes, int n_in,
                              void* d_out, int out_size, void* d_ws, size_t ws_size,
                              hipStream_t stream)
{
    (void)in_sizes; (void)n_in; (void)out_size; (void)ws_size;

    const float* x      = (const float*)d_in[0];   // [8,1024,768]
    const float* w_qkv  = (const float*)d_in[1];   // [2304,768]
    const float* w_v1   = (const float*)d_in[2];   // [768,768]
    const float* w_v2   = (const float*)d_in[3];
    const float* w_proj = (const float*)d_in[4];
    const float* b_proj = (const float*)d_in[5];   // [768]
    const float* cw     = (const float*)d_in[6];   // [33,2]

    float* out  = (float*)d_out;                   // [8,1024,768] then attn
    float* attn = out + (long)Bb * Nn * Cc;        // [8,12,1024,1024]

    // workspace layout (floats)
    float* WS    = (float*)d_ws;
    float* QKV   = WS;                              // 8192 x 2304
    float* MV    = QKV   + (long)8192 * 2304;       // 8192 x 768
    float* IFV   = MV    + (long)8192 * 768;        // 8192 x 768
    float* OUTB  = IFV   + (long)8192 * 768;        // 8192 x 768
    float* WDIFF = OUTB  + (long)8192 * 768;        // 768 x 768
    float* DINV  = WDIFF + (long)768 * 768;         // 8192
    float* G     = DINV  + 8192;                    // 64
    float* YBUF  = QKV;  // reuses QKV region after scores are done

    // N x N scratch lives in the d_out attn region until scores overwrite it
    float* AH = attn;                               // 8 x 1024 x 1024
    float* L2 = attn + (long)Bb * Nn * Nn;          // 8 x 1024 x 1024

    const long sQKVb = (long)Nn * LD;               // 2359296
    const long sNN   = (long)Nn * Nn;               // 1048576
    const long sNC   = (long)Nn * Cc;               // 786432

    // small precomputes
    build_g<<<1, 64, 0, stream>>>(cw, G);
    wdiff_k<<<(Cc * Cc + 255) / 256, 256, 0, stream>>>(w_v1, w_v2, WDIFF);

    // 1) qkv = x @ w_qkv^T  -> [8192,2304]
    gemm_mfma<128, 128, 0><<<dim3(64, 18, 1), 256, 0, stream>>>(
        x, Cc, 0, 0, w_qkv, Cc, 0, 0, QKV, LD, 0, 0,
        nullptr, nullptr, Cc, 1, 1.0f, 0);

    // 2) attn_hat (raw): T[b] = Qf @ Kf^T (full channel) -> AH
    gemm_mfma<128, 128, 0><<<dim3(8, 8, Bb), 256, 0, stream>>>(
        QKV + 0, LD, sQKVb, 0, QKV + Cc, LD, sQKVb, 0, AH, Nn, sNN, 0,
        nullptr, nullptr, Cc, 1, 1.0f, 0);

    // 3) symmetrize + relu, degree rsqrt, scale
    sym_relu<<<32768, 256, 0, stream>>>(AH);
    deg_dinv<<<Bb * Nn, 256, 0, stream>>>(AH, DINV);
    scale_ah<<<32768, 256, 0, stream>>>(AH, DINV);

    // 4) L2 = norm_ah @ norm_ah  (norm_ah symmetric => A@A^T)
    gemm_mfma<128, 128, 0><<<dim3(8, 8, Bb), 256, 0, stream>>>(
        AH, Nn, sNN, 0, AH, Nn, sNN, 0, L2, Nn, sNN, 0,
        nullptr, nullptr, Nn, 1, 1.0f, 0);

    // 5) MV = L2 @ v_flat
    gemm_mfma<128, 128, 1><<<dim3(8, 6, Bb), 256, 0, stream>>>(
        L2, Nn, sNN, 0, QKV + 2 * Cc, LD, sQKVb, 0, MV, Cc, sNC, 0,
        nullptr, nullptr, Nn, 1, 1.0f, 0);

    // 6) IFV = spectral gate of V (circulant filter along hd)
    ifv_kernel<<<Bb * Nn, 256, 0, stream>>>(QKV, G, IFV);

    // 7) OUTB = -V @ w_v1^T + MV @ (w_v1-w_v2)^T
    gemm_mfma<128, 128, 0><<<dim3(64, 6, 1), 256, 0, stream>>>(
        QKV + 2 * Cc, LD, 0, 0, w_v1, Cc, 0, 0, OUTB, Cc, 0, 0,
        nullptr, nullptr, Cc, 1, -1.0f, 0);
    gemm_mfma<128, 128, 0><<<dim3(64, 6, 1), 256, 0, stream>>>(
        MV, Cc, 0, 0, WDIFF, Cc, 0, 0, OUTB, Cc, 0, 0,
        nullptr, nullptr, Cc, 1, 1.0f, 1);

    // 8) per-head scores (scaled) -> attn region (overwrites AH/L2 scratch)
    gemm_mfma<128, 128, 0><<<dim3(8, 8, Bb * Hh), 256, 0, stream>>>(
        QKV + 0, LD, sQKVb, HD, QKV + Cc, LD, sQKVb, HD,
        attn, Nn, (long)Hh * sNN, sNN,
        nullptr, nullptr, HD, Hh, 0.125f, 0);

    // 9) softmax rows in-place
    softmax_rows<<<Bb * Hh * Nn, 256, 0, stream>>>(attn);

    // 10) Y = attn @ IFV (per head) -> YBUF (aliases QKV; Q/K/V all dead now)
    gemm_mfma<128, 64, 1><<<dim3(8, 1, Bb * Hh), 256, 0, stream>>>(
        attn, Nn, (long)Hh * sNN, sNN, IFV, Cc, sNC, HD,
        YBUF, Cc, sNC, HD, nullptr, nullptr, Nn, Hh, 1.0f, 0);

    // 11) out = Y @ w_proj^T + b_proj + OUTB
    gemm_mfma<128, 128, 0><<<dim3(64, 6, 1), 256, 0, stream>>>(
        YBUF, Cc, 0, 0, w_proj, Cc, 0, 0, out, Cc, 0, 0,
        OUTB, b_proj, Cc, 1, 1.0f, 0);
}

// Round 2
// 1561.486 us; speedup vs baseline: 1.7921x; 1.2493x over previous
//
#include <hip/hip_runtime.h>
#include <math.h>

// Problem constants: B=8, N=1024, C=768, H=12, hd=64
#define Bb 8
#define Nn 1024
#define Cc 768
#define Hh 12
#define HD 64
#define LD 2304   // qkv buffer leading dim (3*C)

typedef __attribute__((ext_vector_type(4))) float f32x4;
typedef __attribute__((ext_vector_type(8))) short bf16x8;
typedef unsigned short u16;

// ---------------------------------------------------------------------------
// fp32 -> bf16 (round-nearest-even) and back
__device__ __forceinline__ u16 f2bf(float x) {
    unsigned u = __float_as_uint(x);
    return (u16)((u + 0x7FFFu + ((u >> 16) & 1u)) >> 16);
}
__device__ __forceinline__ float bf2f(u16 h) {
    return __uint_as_float(((unsigned)h) << 16);
}
__device__ __forceinline__ void split4(float4 v, ushort4& h, ushort4& l) {
    h.x = f2bf(v.x); l.x = f2bf(v.x - bf2f(h.x));
    h.y = f2bf(v.y); l.y = f2bf(v.y - bf2f(h.y));
    h.z = f2bf(v.z); l.z = f2bf(v.z - bf2f(h.z));
    h.w = f2bf(v.w); l.w = f2bf(v.w - bf2f(h.w));
}

// ---------------------------------------------------------------------------
// Split-bf16 MFMA GEMM, pre-split operands.
// C[row][col] = alpha * sum_k A[row][k]*B[col][k]  (both operands [rows][K] bf16 hi/lo)
// CA==1: A is fp32 (Af), converted during staging (use when A re-read factor == 1).
// OUT: 0 = fp32 C (+accum/bias/add), 1 = split bf16 (Ch/Cl), 2 = both fp32 C and split.
// grid = (M/BM, N/BN, batches); z -> b1=z/zdiv, b2=z%zdiv; ptr += b1*s1 + b2*s2.
// Requires M%BM==0, N%BN==0, K%32==0, 16B-aligned rows.
template<int BM, int BN, int WGM, int WGN, int CA, int OUT>
__global__ __launch_bounds__(WGM * WGN * 64)
void gemm_ms(const u16* __restrict__ Ah, const u16* __restrict__ Al,
             const float* __restrict__ Af, int lda, long sA1, long sA2,
             const u16* __restrict__ Bh, const u16* __restrict__ Bl,
             int ldb, long sB1, long sB2,
             float* __restrict__ C, u16* __restrict__ Ch, u16* __restrict__ Cl,
             int ldc, long sC1, long sC2,
             const float* __restrict__ add, const float* __restrict__ bias,
             int K, int zdiv, float alpha, int accum)
{
    constexpr int T  = WGM * WGN * 64;
    constexpr int BK = 32;          // fp32 k per step (== bf16 MFMA K)
    constexpr int LK = 40;          // padded LDS leading dim (80B rows -> 2-way max)
    constexpr int WM = BM / WGM, WN = BN / WGN;
    constexpr int FM = WM / 16, FN = WN / 16;

    __shared__ short Ahs[BM * LK];
    __shared__ short Als[BM * LK];
    __shared__ short Bhs[BN * LK];
    __shared__ short Bls[BN * LK];

    int z = blockIdx.z;
    int b1 = z / zdiv, b2 = z - b1 * zdiv;
    long aoff = (long)b1 * sA1 + (long)b2 * sA2;
    if (CA) { Af += aoff; } else { Ah += aoff; Al += aoff; }
    long boff = (long)b1 * sB1 + (long)b2 * sB2;
    Bh += boff; Bl += boff;
    long coff = (long)b1 * sC1 + (long)b2 * sC2;
    if (OUT != 1) { C += coff; if (add) add += coff; }
    if (OUT >= 1) { Ch += coff; Cl += coff; }

    int m0 = blockIdx.x * BM;
    int n0 = blockIdx.y * BN;
    int tid = threadIdx.x;
    int lane = tid & 63, wid = tid >> 6;
    int wrow = (wid / WGN) * WM;
    int wcol = (wid - (wid / WGN) * WGN) * WN;
    int lr = lane & 15;        // frag row (A) / col (B)
    int lk = lane >> 4;        // k-group: 8 contiguous bf16 at lk*8

    f32x4 acc[FM][FN] = {};

    for (int k0 = 0; k0 < K; k0 += BK) {
        // ---- stage A [BM][32] ----
#pragma unroll
        for (int idx = tid; idx < BM * 4; idx += T) {
            int row = idx >> 2, kq = idx & 3;
            if (CA) {
                const float* src = &Af[(long)(m0 + row) * lda + k0 + kq * 8];
                float4 v0 = *(const float4*)src;
                float4 v1 = *(const float4*)(src + 4);
                ushort4 h0, l0, h1, l1; split4(v0, h0, l0); split4(v1, h1, l1);
                *(ushort4*)&Ahs[row * LK + kq * 8]     = h0;
                *(ushort4*)&Ahs[row * LK + kq * 8 + 4] = h1;
                *(ushort4*)&Als[row * LK + kq * 8]     = l0;
                *(ushort4*)&Als[row * LK + kq * 8 + 4] = l1;
            } else {
                long g = (long)(m0 + row) * lda + k0 + kq * 8;
                *(bf16x8*)&Ahs[row * LK + kq * 8] = *(const bf16x8*)&Ah[g];
                *(bf16x8*)&Als[row * LK + kq * 8] = *(const bf16x8*)&Al[g];
            }
        }
        // ---- stage B [BN][32] ----
#pragma unroll
        for (int idx = tid; idx < BN * 4; idx += T) {
            int row = idx >> 2, kq = idx & 3;
            long g = (long)(n0 + row) * ldb + k0 + kq * 8;
            *(bf16x8*)&Bhs[row * LK + kq * 8] = *(const bf16x8*)&Bh[g];
            *(bf16x8*)&Bls[row * LK + kq * 8] = *(const bf16x8*)&Bl[g];
        }
        __syncthreads();

        // ---- 3-term MFMA: acc += Ah*Bh + Al*Bh + Ah*Bl ----
        bf16x8 ah[FM], al[FM];
#pragma unroll
        for (int fm = 0; fm < FM; ++fm) {
            int off = (wrow + fm * 16 + lr) * LK + lk * 8;
            ah[fm] = *(const bf16x8*)&Ahs[off];
            al[fm] = *(const bf16x8*)&Als[off];
        }
#pragma unroll
        for (int fn = 0; fn < FN; ++fn) {
            int off = (wcol + fn * 16 + lr) * LK + lk * 8;
            bf16x8 bh = *(const bf16x8*)&Bhs[off];
            bf16x8 bl = *(const bf16x8*)&Bls[off];
#pragma unroll
            for (int fm = 0; fm < FM; ++fm) {
                acc[fm][fn] = __builtin_amdgcn_mfma_f32_16x16x32_bf16(ah[fm], bh, acc[fm][fn], 0, 0, 0);
                acc[fm][fn] = __builtin_amdgcn_mfma_f32_16x16x32_bf16(al[fm], bh, acc[fm][fn], 0, 0, 0);
                acc[fm][fn] = __builtin_amdgcn_mfma_f32_16x16x32_bf16(ah[fm], bl, acc[fm][fn], 0, 0, 0);
            }
        }
        __syncthreads();
    }

    // ---- epilogue: C/D layout col=lane&15, row=(lane>>4)*4+reg ----
#pragma unroll
    for (int fm = 0; fm < FM; ++fm) {
#pragma unroll
        for (int fn = 0; fn < FN; ++fn) {
            int col = n0 + wcol + fn * 16 + lr;
            float bv = 0.0f;
            if (OUT != 1) { if (bias) bv = bias[col]; }
#pragma unroll
            for (int r = 0; r < 4; ++r) {
                int row = m0 + wrow + fm * 16 + lk * 4 + r;
                long idx = (long)row * ldc + col;
                float v = alpha * acc[fm][fn][r];
                if (OUT != 1) {
                    if (accum) v += C[idx];
                    v += bv;
                    if (add) v += add[idx];
                    C[idx] = v;
                }
                if (OUT >= 1) {
                    u16 hh = f2bf(v);
                    Ch[idx] = hh;
                    Cl[idx] = f2bf(v - bf2f(hh));
                }
            }
        }
    }
}

// ---------------------------------------------------------------------------
__device__ inline float waveReduceSum(float v) {
#pragma unroll
    for (int off = 32; off; off >>= 1) v += __shfl_down(v, off, 64);
    return v;
}
__device__ inline float waveReduceMax(float v) {
#pragma unroll
    for (int off = 32; off; off >>= 1) v = fmaxf(v, __shfl_down(v, off, 64));
    return v;
}

// in-place row softmax, one block per row of 1024
__global__ __launch_bounds__(256)
void softmax_rows(float* __restrict__ p)
{
    long row = blockIdx.x;
    float* r = p + row * 1024;
    int tid = threadIdx.x;
    float4 x = ((float4*)r)[tid];
    float m = fmaxf(fmaxf(x.x, x.y), fmaxf(x.z, x.w));
    m = waveReduceMax(m);
    __shared__ float sm[4];
    __shared__ float bm, bs;
    int lane = tid & 63, wid = tid >> 6;
    if (!lane) sm[wid] = m;
    __syncthreads();
    if (tid == 0) bm = fmaxf(fmaxf(sm[0], sm[1]), fmaxf(sm[2], sm[3]));
    __syncthreads();
    float mm = bm;
    x.x = expf(x.x - mm); x.y = expf(x.y - mm);
    x.z = expf(x.z - mm); x.w = expf(x.w - mm);
    float s = x.x + x.y + x.z + x.w;
    s = waveReduceSum(s);
    if (!lane) sm[wid] = s;
    __syncthreads();
    if (tid == 0) bs = sm[0] + sm[1] + sm[2] + sm[3];
    __syncthreads();
    float inv = 1.0f / bs;
    x.x *= inv; x.y *= inv; x.z *= inv; x.w *= inv;
    ((float4*)r)[tid] = x;
}

// AH[b,i,j] = relu((AH[b,i,j]+AH[b,j,i])/2), in-place, pair-symmetric
__global__ __launch_bounds__(256)
void sym_relu(float* __restrict__ AH)
{
    long idx = (long)blockIdx.x * 256 + threadIdx.x;
    if (idx >= (long)Bb * Nn * Nn) return;
    int b = (int)(idx >> 20);
    int r = (int)(idx & 1048575);
    int i = r >> 10, j = r & 1023;
    if (j < i) return;
    float* Ab = AH + ((long)b << 20);
    float t = 0.5f * (Ab[i * 1024 + j] + Ab[j * 1024 + i]);
    t = fmaxf(t, 0.0f);
    Ab[i * 1024 + j] = t;
    Ab[j * 1024 + i] = t;
}

// dinv[b,i] = deg!=0 ? rsqrt(deg) : 0 ; deg = row sum of AH
__global__ __launch_bounds__(256)
void deg_dinv(const float* __restrict__ AH, float* __restrict__ dinv)
{
    long row = blockIdx.x;                 // 0..8191  (b*1024+i)
    const float* r = AH + row * 1024;
    int tid = threadIdx.x;
    float4 x = ((const float4*)r)[tid];
    float s = x.x + x.y + x.z + x.w;
    s = waveReduceSum(s);
    __shared__ float sm[4];
    int lane = tid & 63, wid = tid >> 6;
    if (!lane) sm[wid] = s;
    __syncthreads();
    if (tid == 0) {
        float d = sm[0] + sm[1] + sm[2] + sm[3];
        dinv[row] = (d != 0.0f) ? rsqrtf(d) : 0.0f;
    }
}

// AHh/AHl = split(AH[b,i,j] * dinv[b,i] * dinv[b,j]) ; 4 elems/thread
__global__ __launch_bounds__(256)
void scale_split(const float* __restrict__ AH, const float* __restrict__ dinv,
                 u16* __restrict__ oh, u16* __restrict__ ol)
{
    long i4 = (long)blockIdx.x * 256 + threadIdx.x;
    if (i4 >= (long)Bb * Nn * Nn / 4) return;
    long e = i4 * 4;
    int b = (int)(e >> 20);
    int i = (int)((e >> 10) & 1023);
    int j = (int)(e & 1023);
    float di = dinv[(b << 10) + i];
    const float* dj = &dinv[(b << 10) + j];
    float4 v = ((const float4*)AH)[i4];
    v.x *= di * dj[0]; v.y *= di * dj[1]; v.z *= di * dj[2]; v.w *= di * dj[3];
    ushort4 h, l; split4(v, h, l);
    ((ushort4*)oh)[i4] = h;
    ((ushort4*)ol)[i4] = l;
}

// generic fp32 -> split bf16 hi/lo, float4-vectorized grid-stride
__global__ __launch_bounds__(256)
void split_plain(const float* __restrict__ in, u16* __restrict__ h,
                 u16* __restrict__ l, long n4)
{
    for (long i = (long)blockIdx.x * 256 + threadIdx.x; i < n4;
         i += (long)gridDim.x * 256) {
        float4 v = ((const float4*)in)[i];
        ushort4 hh, ll; split4(v, hh, ll);
        ((ushort4*)h)[i] = hh;
        ((ushort4*)l)[i] = ll;
    }
}

// (a-b) -> split bf16
__global__ __launch_bounds__(256)
void wdiff_split(const float* __restrict__ a, const float* __restrict__ b,
                 u16* __restrict__ h, u16* __restrict__ l, long n4)
{
    for (long i = (long)blockIdx.x * 256 + threadIdx.x; i < n4;
         i += (long)gridDim.x * 256) {
        float4 va = ((const float4*)a)[i];
        float4 vb = ((const float4*)b)[i];
        float4 v = make_float4(va.x - vb.x, va.y - vb.y, va.z - vb.z, va.w - vb.w);
        ushort4 hh, ll; split4(v, hh, ll);
        ((ushort4*)h)[i] = hh;
        ((ushort4*)l)[i] = ll;
    }
}

// transpose + split: in fp32 [R][Ck] (row stride ldi, batch stride sIn)
//                 -> oh/ol bf16 [Ck][R] (row stride R, batch stride sOut)
// grid: (R/64, Ck/64, batches), 256 threads
__global__ __launch_bounds__(256)
void tsplit(const float* __restrict__ in, long sIn, int ldi,
            u16* __restrict__ oh, u16* __restrict__ ol, long sOut, int R)
{
    __shared__ float Ts[64][65];
    int z = blockIdx.z;
    in += (long)z * sIn;
    oh += (long)z * sOut;
    ol += (long)z * sOut;
    int r0 = blockIdx.x * 64;   // input row block
    int c0 = blockIdx.y * 64;   // input col block
    int tid = threadIdx.x;
#pragma unroll
    for (int idx = tid; idx < 1024; idx += 256) {
        int r = idx >> 4, c4 = idx & 15;
        float4 v = *(const float4*)&in[(long)(r0 + r) * ldi + c0 + c4 * 4];
        Ts[c4 * 4 + 0][r] = v.x;
        Ts[c4 * 4 + 1][r] = v.y;
        Ts[c4 * 4 + 2][r] = v.z;
        Ts[c4 * 4 + 3][r] = v.w;
    }
    __syncthreads();
#pragma unroll
    for (int idx = tid; idx < 1024; idx += 256) {
        int c = idx >> 4, r4 = idx & 15;
        float4 v = make_float4(Ts[c][r4 * 4], Ts[c][r4 * 4 + 1],
                               Ts[c][r4 * 4 + 2], Ts[c][r4 * 4 + 3]);
        ushort4 h, l; split4(v, h, l);
        long o = (long)(c0 + c) * R + r0 + r4 * 4;
        *(ushort4*)&oh[o] = h;
        *(ushort4*)&ol[o] = l;
    }
}

// circulant taps of the rfft*w->irfft gate (ortho norm, numpy c2r semantics)
__global__ void build_g(const float* __restrict__ cw, float* __restrict__ g)
{
    int d = threadIdx.x;
    if (d >= 64) return;
    float s = cw[0] + ((d & 1) ? -cw[64] : cw[64]);
#pragma unroll
    for (int f = 1; f < 32; ++f) {
        int ph = (f * d) & 63;
        float ang = 6.283185307179586f * (float)ph / 64.0f;
        s += 2.0f * (cw[2 * f] * cosf(ang) + cw[2 * f + 1] * sinf(ang));
    }
    g[d] = s * 0.015625f;   // 1/64
}

// ifv[b,n,h*64+t] = sum_m V[b,n,h*64+m] * g[(m-t)&63], one block per (b,n)
__global__ __launch_bounds__(256)
void ifv_kernel(const float* __restrict__ qkv, const float* __restrict__ g,
                float* __restrict__ ifv)
{
    int bn = blockIdx.x;   // 0..8191
    __shared__ float Vr[768];
    __shared__ float Gs[64];
    const float* vrow = qkv + (long)bn * LD + 2 * Cc;   // V slice
    int tid = threadIdx.x;
    if (tid < 64) Gs[tid] = g[tid];
    for (int c = tid; c < 768; c += 256) Vr[c] = vrow[c];
    __syncthreads();
    for (int c = tid; c < 768; c += 256) {
        int h = c >> 6, t = c & 63;
        const float* vh = Vr + (h << 6);
        float s = 0.0f;
#pragma unroll
        for (int m2 = 0; m2 < 64; ++m2)
            s = fmaf(vh[m2], Gs[(m2 - t) & 63], s);
        ifv[(long)bn * 768 + c] = s;
    }
}

// ---------------------------------------------------------------------------
extern "C" void kernel_launch(void* const* d_in, const int* in_sizes, int n_in,
                              void* d_out, int out_size, void* d_ws, size_t ws_size,
                              hipStream_t stream)
{
    (void)in_sizes; (void)n_in; (void)out_size; (void)ws_size;

    const float* x      = (const float*)d_in[0];   // [8,1024,768]
    const float* w_qkv  = (const float*)d_in[1];   // [2304,768]
    const float* w_v1   = (const float*)d_in[2];   // [768,768]
    const float* w_v2   = (const float*)d_in[3];
    const float* w_proj = (const float*)d_in[4];
    const float* b_proj = (const float*)d_in[5];   // [768]
    const float* cw     = (const float*)d_in[6];   // [33,2]

    float* out  = (float*)d_out;                   // [8,1024,768] then attn
    float* attn = out + (long)Bb * Nn * Cc;        // [8,12,1024,1024]

    // ---- workspace layout (bytes) ----
    char* W = (char*)d_ws;
    long off = 0;
    auto alloc = [&](long bytes) { char* p = W + off; off += (bytes + 255) & ~255L; return p; };

    float* QKVf  = (float*)alloc((long)8192 * 2304 * 4);
    u16*   QKVh  = (u16*)  alloc((long)8192 * 2304 * 2);
    u16*   QKVl  = (u16*)  alloc((long)8192 * 2304 * 2);
    u16*   AHh   = (u16*)  alloc((long)Bb * Nn * Nn * 2);
    u16*   AHl   = (u16*)  alloc((long)Bb * Nn * Nn * 2);
    u16*   L2h   = (u16*)  alloc((long)Bb * Nn * Nn * 2);
    u16*   L2l   = (u16*)  alloc((long)Bb * Nn * Nn * 2);
    u16*   MVh   = (u16*)  alloc((long)8192 * 768 * 2);
    u16*   MVl   = (u16*)  alloc((long)8192 * 768 * 2);
    float* IFVf  = (float*)alloc((long)8192 * 768 * 4);
    u16*   IFVTh = (u16*)  alloc((long)Bb * 768 * 1024 * 2);
    u16*   IFVTl = (u16*)  alloc((long)Bb * 768 * 1024 * 2);
    u16*   VTh   = (u16*)  alloc((long)Bb * 768 * 1024 * 2);
    u16*   VTl   = (u16*)  alloc((long)Bb * 768 * 1024 * 2);
    u16*   Yh    = (u16*)  alloc((long)8192 * 768 * 2);
    u16*   Yl    = (u16*)  alloc((long)8192 * 768 * 2);
    float* OUTB  = (float*)alloc((long)8192 * 768 * 4);
    u16*   xh    = (u16*)  alloc((long)8192 * 768 * 2);
    u16*   xl    = (u16*)  alloc((long)8192 * 768 * 2);
    u16*   wqh   = (u16*)  alloc((long)2304 * 768 * 2);
    u16*   wql   = (u16*)  alloc((long)2304 * 768 * 2);
    u16*   wv1h  = (u16*)  alloc((long)768 * 768 * 2);
    u16*   wv1l  = (u16*)  alloc((long)768 * 768 * 2);
    u16*   wdh   = (u16*)  alloc((long)768 * 768 * 2);
    u16*   wdl   = (u16*)  alloc((long)768 * 768 * 2);
    u16*   wph   = (u16*)  alloc((long)768 * 768 * 2);
    u16*   wpl   = (u16*)  alloc((long)768 * 768 * 2);
    float* DINV  = (float*)alloc(8192 * 4);
    float* G     = (float*)alloc(256);

    // N x N fp32 scratch for AH lives in the d_out attn region until scores overwrite it
    float* AH = attn;                               // 8 x 1024 x 1024 fp32

    const long sQKV = (long)Nn * LD;                // 2359296 (elems)
    const long sNN  = (long)Nn * Nn;                // 1048576
    const long sNC  = (long)Nn * Cc;                // 786432

    // ---- input splits / small precomputes ----
    build_g<<<1, 64, 0, stream>>>(cw, G);
    split_plain<<<2048, 256, 0, stream>>>(x,      xh,   xl,   (long)8192 * 768 / 4);
    split_plain<<<1024, 256, 0, stream>>>(w_qkv,  wqh,  wql,  (long)2304 * 768 / 4);
    split_plain<<<512,  256, 0, stream>>>(w_v1,   wv1h, wv1l, (long)768 * 768 / 4);
    split_plain<<<512,  256, 0, stream>>>(w_proj, wph,  wpl,  (long)768 * 768 / 4);
    wdiff_split<<<512,  256, 0, stream>>>(w_v1, w_v2, wdh, wdl, (long)768 * 768 / 4);

    // 1) QKV = x @ w_qkv^T : fp32 + split outputs
    gemm_ms<128, 128, 2, 2, 0, 2><<<dim3(64, 18, 1), 256, 0, stream>>>(
        xh, xl, nullptr, Cc, 0, 0, wqh, wql, Cc, 0, 0,
        QKVf, QKVh, QKVl, LD, 0, 0, nullptr, nullptr, Cc, 1, 1.0f, 0);

    // 2) AH = Qf @ Kf^T (full channel), fp32 into attn-region scratch
    gemm_ms<128, 128, 2, 2, 0, 0><<<dim3(8, 8, Bb), 256, 0, stream>>>(
        QKVh, QKVl, nullptr, LD, sQKV, 0, QKVh + Cc, QKVl + Cc, LD, sQKV, 0,
        AH, nullptr, nullptr, Nn, sNN, 0, nullptr, nullptr, Cc, 1, 1.0f, 0);

    // 3) symmetrize+relu, degree rsqrt, scale -> split AH
    sym_relu<<<32768, 256, 0, stream>>>(AH);
    deg_dinv<<<Bb * Nn, 256, 0, stream>>>(AH, DINV);
    scale_split<<<8192, 256, 0, stream>>>(AH, DINV, AHh, AHl);

    // 4) L2 = norm_ah @ norm_ah (symmetric => A@A^T), split output
    gemm_ms<128, 128, 2, 2, 0, 1><<<dim3(8, 8, Bb), 256, 0, stream>>>(
        AHh, AHl, nullptr, Nn, sNN, 0, AHh, AHl, Nn, sNN, 0,
        nullptr, L2h, L2l, Nn, sNN, 0, nullptr, nullptr, Nn, 1, 1.0f, 0);

    // 5) VT = transpose-split of V ; MV = L2 @ V = L2 @ VT^T, split output
    tsplit<<<dim3(16, 12, Bb), 256, 0, stream>>>(
        QKVf + 2 * Cc, sQKV, LD, VTh, VTl, (long)Cc * Nn, Nn);
    gemm_ms<128, 128, 2, 2, 0, 1><<<dim3(8, 6, Bb), 256, 0, stream>>>(
        L2h, L2l, nullptr, Nn, sNN, 0, VTh, VTl, Nn, (long)Cc * Nn, 0,
        nullptr, MVh, MVl, Cc, sNC, 0, nullptr, nullptr, Nn, 1, 1.0f, 0);

    // 6) IFV = spectral gate of V ; transpose-split for the PV GEMM
    ifv_kernel<<<Bb * Nn, 256, 0, stream>>>(QKVf, G, IFVf);
    tsplit<<<dim3(16, 12, Bb), 256, 0, stream>>>(
        IFVf, sNC, Cc, IFVTh, IFVTl, (long)Cc * Nn, Nn);

    // 7) OUTB = -V @ w_v1^T + MV @ (w_v1-w_v2)^T
    gemm_ms<128, 128, 2, 2, 0, 0><<<dim3(64, 6, 1), 256, 0, stream>>>(
        QKVh + 2 * Cc, QKVl + 2 * Cc, nullptr, LD, 0, 0, wv1h, wv1l, Cc, 0, 0,
        OUTB, nullptr, nullptr, Cc, 0, 0, nullptr, nullptr, Cc, 1, -1.0f, 0);
    gemm_ms<128, 128, 2, 2, 0, 0><<<dim3(64, 6, 1), 256, 0, stream>>>(
        MVh, MVl, nullptr, Cc, 0, 0, wdh, wdl, Cc, 0, 0,
        OUTB, nullptr, nullptr, Cc, 0, 0, nullptr, nullptr, Cc, 1, 1.0f, 1);

    // 8) per-head scaled scores -> attn (overwrites AH scratch; AH dead)
    gemm_ms<128, 128, 2, 2, 0, 0><<<dim3(8, 8, Bb * Hh), 256, 0, stream>>>(
        QKVh, QKVl, nullptr, LD, sQKV, HD, QKVh + Cc, QKVl + Cc, LD, sQKV, HD,
        attn, nullptr, nullptr, Nn, (long)Hh * sNN, sNN,
        nullptr, nullptr, HD, Hh, 0.125f, 0);

    // 9) softmax rows in-place
    softmax_rows<<<Bb * Hh * Nn, 256, 0, stream>>>(attn);

    // 10) Y = attn @ IFV per head (A = fp32 attn, converted in staging; read-once)
    gemm_ms<128, 64, 2, 1, 1, 1><<<dim3(8, 1, Bb * Hh), 128, 0, stream>>>(
        nullptr, nullptr, attn, Nn, (long)Hh * sNN, sNN,
        IFVTh, IFVTl, Nn, (long)Cc * Nn, (long)HD * Nn,
        nullptr, Yh, Yl, Cc, sNC, HD, nullptr, nullptr, Nn, Hh, 1.0f, 0);

    // 11) out = Y @ w_proj^T + b_proj + OUTB
    gemm_ms<128, 128, 2, 2, 0, 0><<<dim3(64, 6, 1), 256, 0, stream>>>(
        Yh, Yl, nullptr, Cc, 0, 0, wph, wpl, Cc, 0, 0,
        out, nullptr, nullptr, Cc, 0, 0, OUTB, b_proj, Cc, 1, 1.0f, 0);
}

// Round 3
// 1349.538 us; speedup vs baseline: 2.0736x; 1.1571x over previous
//
#include <hip/hip_runtime.h>
#include <math.h>

// Problem constants: B=8, N=1024, C=768, H=12, hd=64
#define Bb 8
#define Nn 1024
#define Cc 768
#define Hh 12
#define HD 64
#define LD 2304   // qkv buffer leading dim (3*C)

typedef __attribute__((ext_vector_type(4))) float f32x4;
typedef __attribute__((ext_vector_type(8))) short bf16x8;
typedef unsigned short u16;

// ---------------------------------------------------------------------------
// fp32 -> bf16 (round-nearest-even) and back
__device__ __forceinline__ u16 f2bf(float x) {
    unsigned u = __float_as_uint(x);
    return (u16)((u + 0x7FFFu + ((u >> 16) & 1u)) >> 16);
}
__device__ __forceinline__ float bf2f(u16 h) {
    return __uint_as_float(((unsigned)h) << 16);
}
__device__ __forceinline__ void split4(float4 v, ushort4& h, ushort4& l) {
    h.x = f2bf(v.x); l.x = f2bf(v.x - bf2f(h.x));
    h.y = f2bf(v.y); l.y = f2bf(v.y - bf2f(h.y));
    h.z = f2bf(v.z); l.z = f2bf(v.z - bf2f(h.z));
    h.w = f2bf(v.w); l.w = f2bf(v.w - bf2f(h.w));
}

// ---------------------------------------------------------------------------
// Split-bf16 MFMA GEMM with register prefetch (issue-early / write-late).
// C[row][col] = alpha * sum_k A[row][k]*B[col][k]  (operands [rows][K] bf16 hi/lo)
// CA==1: A is fp32 (Af), converted during staging (for read-once A like attn).
// OUT: 0 = fp32 C (+accum/bias/add), 1 = split bf16 (Ch/Cl).
// grid = (M/BM, N/BN, batches); z -> b1=z/zdiv, b2=z%zdiv; ptr += b1*s1 + b2*s2.
// Requires M%BM==0, N%BN==0, K%BK==0, 16B-aligned rows.
template<int BM, int BN, int BK, int WGM, int WGN, int CA, int OUT>
__global__ __launch_bounds__(WGM * WGN * 64)
void gemm_ms(const u16* __restrict__ Ah, const u16* __restrict__ Al,
             const float* __restrict__ Af, int lda, long sA1, long sA2,
             const u16* __restrict__ Bh, const u16* __restrict__ Bl,
             int ldb, long sB1, long sB2,
             float* __restrict__ C, u16* __restrict__ Ch, u16* __restrict__ Cl,
             int ldc, long sC1, long sC2,
             const float* __restrict__ add, const float* __restrict__ bias,
             int K, int zdiv, float alpha, int accum)
{
    constexpr int T  = WGM * WGN * 64;
    constexpr int LK = BK + 8;        // padded LDS leading dim (bf16)
    constexpr int WM = BM / WGM, WN = BN / WGN;
    constexpr int FM = WM / 16, FN = WN / 16;
    constexpr int KQ = BK / 8;        // bf16x8 chunks per row
    constexpr int AI = BM * BK / 8 / T;
    constexpr int BI = BN * BK / 8 / T;
    constexpr int KS = BK / 32;       // MFMA sub-steps per tile

    __shared__ short Ahs[BM * LK], Als[BM * LK], Bhs[BN * LK], Bls[BN * LK];

    int z = blockIdx.z;
    int b1 = z / zdiv, b2 = z - b1 * zdiv;
    long aoff = (long)b1 * sA1 + (long)b2 * sA2;
    if (CA) { Af += aoff; } else { Ah += aoff; Al += aoff; }
    long boff = (long)b1 * sB1 + (long)b2 * sB2;
    Bh += boff; Bl += boff;
    long coff = (long)b1 * sC1 + (long)b2 * sC2;
    if (OUT == 0) { C += coff; if (add) add += coff; }
    else          { Ch += coff; Cl += coff; }

    int m0 = blockIdx.x * BM;
    int n0 = blockIdx.y * BN;
    int tid = threadIdx.x;
    int lane = tid & 63, wid = tid >> 6;
    int wrow = (wid / WGN) * WM;
    int wcol = (wid - (wid / WGN) * WGN) * WN;
    int lr = lane & 15;        // frag row (A) / col (B)
    int lk = lane >> 4;        // k-group: 8 contiguous bf16 at lk*8

    f32x4 acc[FM][FN] = {};

    bf16x8 rah[AI], ral[AI], rbh[BI], rbl[BI];
    float4 rfa[AI][2];         // used when CA==1

    auto LOAD = [&](int k0) {
#pragma unroll
        for (int i = 0; i < AI; ++i) {
            int idx = i * T + tid;
            int row = idx / KQ, kq = idx - row * KQ;
            if (CA) {
                const float* s = &Af[(long)(m0 + row) * lda + k0 + kq * 8];
                rfa[i][0] = *(const float4*)s;
                rfa[i][1] = *(const float4*)(s + 4);
            } else {
                long g = (long)(m0 + row) * lda + k0 + kq * 8;
                rah[i] = *(const bf16x8*)&Ah[g];
                ral[i] = *(const bf16x8*)&Al[g];
            }
        }
#pragma unroll
        for (int i = 0; i < BI; ++i) {
            int idx = i * T + tid;
            int row = idx / KQ, kq = idx - row * KQ;
            long g = (long)(n0 + row) * ldb + k0 + kq * 8;
            rbh[i] = *(const bf16x8*)&Bh[g];
            rbl[i] = *(const bf16x8*)&Bl[g];
        }
    };
    auto STORE = [&]() {
#pragma unroll
        for (int i = 0; i < AI; ++i) {
            int idx = i * T + tid;
            int row = idx / KQ, kq = idx - row * KQ;
            if (CA) {
                ushort4 h0, l0, h1, l1;
                split4(rfa[i][0], h0, l0); split4(rfa[i][1], h1, l1);
                *(ushort4*)&Ahs[row * LK + kq * 8]     = h0;
                *(ushort4*)&Ahs[row * LK + kq * 8 + 4] = h1;
                *(ushort4*)&Als[row * LK + kq * 8]     = l0;
                *(ushort4*)&Als[row * LK + kq * 8 + 4] = l1;
            } else {
                *(bf16x8*)&Ahs[row * LK + kq * 8] = rah[i];
                *(bf16x8*)&Als[row * LK + kq * 8] = ral[i];
            }
        }
#pragma unroll
        for (int i = 0; i < BI; ++i) {
            int idx = i * T + tid;
            int row = idx / KQ, kq = idx - row * KQ;
            *(bf16x8*)&Bhs[row * LK + kq * 8] = rbh[i];
            *(bf16x8*)&Bls[row * LK + kq * 8] = rbl[i];
        }
    };

    int nt = K / BK;
    LOAD(0);
    for (int t = 0; t < nt; ++t) {
        __syncthreads();           // prior tile's readers done
        STORE();
        __syncthreads();
        if (t + 1 < nt) LOAD((t + 1) * BK);   // in flight during MFMA below

#pragma unroll
        for (int s = 0; s < KS; ++s) {
            bf16x8 fah[FM], fal[FM];
#pragma unroll
            for (int fm = 0; fm < FM; ++fm) {
                int off = (wrow + fm * 16 + lr) * LK + s * 32 + lk * 8;
                fah[fm] = *(const bf16x8*)&Ahs[off];
                fal[fm] = *(const bf16x8*)&Als[off];
            }
#pragma unroll
            for (int fn = 0; fn < FN; ++fn) {
                int off = (wcol + fn * 16 + lr) * LK + s * 32 + lk * 8;
                bf16x8 fbh = *(const bf16x8*)&Bhs[off];
                bf16x8 fbl = *(const bf16x8*)&Bls[off];
#pragma unroll
                for (int fm = 0; fm < FM; ++fm) {
                    acc[fm][fn] = __builtin_amdgcn_mfma_f32_16x16x32_bf16(fah[fm], fbh, acc[fm][fn], 0, 0, 0);
                    acc[fm][fn] = __builtin_amdgcn_mfma_f32_16x16x32_bf16(fal[fm], fbh, acc[fm][fn], 0, 0, 0);
                    acc[fm][fn] = __builtin_amdgcn_mfma_f32_16x16x32_bf16(fah[fm], fbl, acc[fm][fn], 0, 0, 0);
                }
            }
        }
    }

    // ---- epilogue: C/D layout col=lane&15, row=(lane>>4)*4+reg ----
#pragma unroll
    for (int fm = 0; fm < FM; ++fm) {
#pragma unroll
        for (int fn = 0; fn < FN; ++fn) {
            int col = n0 + wcol + fn * 16 + lr;
            float bv = 0.0f;
            if (OUT == 0) { if (bias) bv = bias[col]; }
#pragma unroll
            for (int r = 0; r < 4; ++r) {
                int row = m0 + wrow + fm * 16 + lk * 4 + r;
                long idx = (long)row * ldc + col;
                float v = alpha * acc[fm][fn][r];
                if (OUT == 0) {
                    if (accum) v += C[idx];
                    v += bv;
                    if (add) v += add[idx];
                    C[idx] = v;
                } else {
                    u16 hh = f2bf(v);
                    Ch[idx] = hh;
                    Cl[idx] = f2bf(v - bf2f(hh));
                }
            }
        }
    }
}

// ---------------------------------------------------------------------------
__device__ inline float waveReduceSum(float v) {
#pragma unroll
    for (int off = 32; off; off >>= 1) v += __shfl_down(v, off, 64);
    return v;
}
__device__ inline float waveReduceMax(float v) {
#pragma unroll
    for (int off = 32; off; off >>= 1) v = fmaxf(v, __shfl_down(v, off, 64));
    return v;
}

// in-place row softmax, one block per row of 1024
__global__ __launch_bounds__(256)
void softmax_rows(float* __restrict__ p)
{
    long row = blockIdx.x;
    float* r = p + row * 1024;
    int tid = threadIdx.x;
    float4 x = ((float4*)r)[tid];
    float m = fmaxf(fmaxf(x.x, x.y), fmaxf(x.z, x.w));
    m = waveReduceMax(m);
    __shared__ float sm[4];
    __shared__ float bm, bs;
    int lane = tid & 63, wid = tid >> 6;
    if (!lane) sm[wid] = m;
    __syncthreads();
    if (tid == 0) bm = fmaxf(fmaxf(sm[0], sm[1]), fmaxf(sm[2], sm[3]));
    __syncthreads();
    float mm = bm;
    x.x = expf(x.x - mm); x.y = expf(x.y - mm);
    x.z = expf(x.z - mm); x.w = expf(x.w - mm);
    float s = x.x + x.y + x.z + x.w;
    s = waveReduceSum(s);
    if (!lane) sm[wid] = s;
    __syncthreads();
    if (tid == 0) bs = sm[0] + sm[1] + sm[2] + sm[3];
    __syncthreads();
    float inv = 1.0f / bs;
    x.x *= inv; x.y *= inv; x.z *= inv; x.w *= inv;
    ((float4*)r)[tid] = x;
}

// AH[b,i,j] = relu((AH[b,i,j]+AH[b,j,i])/2), in-place, pair-symmetric
__global__ __launch_bounds__(256)
void sym_relu(float* __restrict__ AH)
{
    long idx = (long)blockIdx.x * 256 + threadIdx.x;
    if (idx >= (long)Bb * Nn * Nn) return;
    int b = (int)(idx >> 20);
    int r = (int)(idx & 1048575);
    int i = r >> 10, j = r & 1023;
    if (j < i) return;
    float* Ab = AH + ((long)b << 20);
    float t = 0.5f * (Ab[i * 1024 + j] + Ab[j * 1024 + i]);
    t = fmaxf(t, 0.0f);
    Ab[i * 1024 + j] = t;
    Ab[j * 1024 + i] = t;
}

// dinv[b,i] = deg!=0 ? rsqrt(deg) : 0 ; deg = row sum of AH
__global__ __launch_bounds__(256)
void deg_dinv(const float* __restrict__ AH, float* __restrict__ dinv)
{
    long row = blockIdx.x;                 // 0..8191  (b*1024+i)
    const float* r = AH + row * 1024;
    int tid = threadIdx.x;
    float4 x = ((const float4*)r)[tid];
    float s = x.x + x.y + x.z + x.w;
    s = waveReduceSum(s);
    __shared__ float sm[4];
    int lane = tid & 63, wid = tid >> 6;
    if (!lane) sm[wid] = s;
    __syncthreads();
    if (tid == 0) {
        float d = sm[0] + sm[1] + sm[2] + sm[3];
        dinv[row] = (d != 0.0f) ? rsqrtf(d) : 0.0f;
    }
}

// AHh/AHl = split(AH[b,i,j] * dinv[b,i] * dinv[b,j]) ; 4 elems/thread
__global__ __launch_bounds__(256)
void scale_split(const float* __restrict__ AH, const float* __restrict__ dinv,
                 u16* __restrict__ oh, u16* __restrict__ ol)
{
    long i4 = (long)blockIdx.x * 256 + threadIdx.x;
    if (i4 >= (long)Bb * Nn * Nn / 4) return;
    long e = i4 * 4;
    int b = (int)(e >> 20);
    int i = (int)((e >> 10) & 1023);
    int j = (int)(e & 1023);
    float di = dinv[(b << 10) + i];
    const float* dj = &dinv[(b << 10) + j];
    float4 v = ((const float4*)AH)[i4];
    v.x *= di * dj[0]; v.y *= di * dj[1]; v.z *= di * dj[2]; v.w *= di * dj[3];
    ushort4 h, l; split4(v, h, l);
    ((ushort4*)oh)[i4] = h;
    ((ushort4*)ol)[i4] = l;
}

// generic fp32 -> split bf16 hi/lo, float4-vectorized grid-stride
__global__ __launch_bounds__(256)
void split_plain(const float* __restrict__ in, u16* __restrict__ h,
                 u16* __restrict__ l, long n4)
{
    for (long i = (long)blockIdx.x * 256 + threadIdx.x; i < n4;
         i += (long)gridDim.x * 256) {
        float4 v = ((const float4*)in)[i];
        ushort4 hh, ll; split4(v, hh, ll);
        ((ushort4*)h)[i] = hh;
        ((ushort4*)l)[i] = ll;
    }
}

// (a-b) -> split bf16
__global__ __launch_bounds__(256)
void wdiff_split(const float* __restrict__ a, const float* __restrict__ b,
                 u16* __restrict__ h, u16* __restrict__ l, long n4)
{
    for (long i = (long)blockIdx.x * 256 + threadIdx.x; i < n4;
         i += (long)gridDim.x * 256) {
        float4 va = ((const float4*)a)[i];
        float4 vb = ((const float4*)b)[i];
        float4 v = make_float4(va.x - vb.x, va.y - vb.y, va.z - vb.z, va.w - vb.w);
        ushort4 hh, ll; split4(v, hh, ll);
        ((ushort4*)h)[i] = hh;
        ((ushort4*)l)[i] = ll;
    }
}

// transpose split u16 arrays: in h/l [R rows][ld ldi] -> out [cols][R], 64x64 tiles
__global__ __launch_bounds__(256)
void t16(const u16* __restrict__ inh, const u16* __restrict__ inl, long sIn, int ldi,
         u16* __restrict__ oh, u16* __restrict__ ol, long sOut, int R)
{
    __shared__ u16 Th[64][68];
    __shared__ u16 Tl[64][68];
    int z = blockIdx.z;
    inh += (long)z * sIn; inl += (long)z * sIn;
    oh  += (long)z * sOut; ol += (long)z * sOut;
    int r0 = blockIdx.x * 64;   // input row block
    int c0 = blockIdx.y * 64;   // input col block
    int tid = threadIdx.x;
#pragma unroll
    for (int i = tid; i < 1024; i += 256) {
        int r = i >> 4, cq = i & 15;
        ushort4 vh = *(const ushort4*)&inh[(long)(r0 + r) * ldi + c0 + cq * 4];
        ushort4 vl = *(const ushort4*)&inl[(long)(r0 + r) * ldi + c0 + cq * 4];
        Th[cq * 4 + 0][r] = vh.x; Th[cq * 4 + 1][r] = vh.y;
        Th[cq * 4 + 2][r] = vh.z; Th[cq * 4 + 3][r] = vh.w;
        Tl[cq * 4 + 0][r] = vl.x; Tl[cq * 4 + 1][r] = vl.y;
        Tl[cq * 4 + 2][r] = vl.z; Tl[cq * 4 + 3][r] = vl.w;
    }
    __syncthreads();
#pragma unroll
    for (int i = tid; i < 1024; i += 256) {
        int c = i >> 4, rq = i & 15;
        ushort4 vh = make_ushort4(Th[c][rq * 4], Th[c][rq * 4 + 1],
                                  Th[c][rq * 4 + 2], Th[c][rq * 4 + 3]);
        ushort4 vl = make_ushort4(Tl[c][rq * 4], Tl[c][rq * 4 + 1],
                                  Tl[c][rq * 4 + 2], Tl[c][rq * 4 + 3]);
        long o = (long)(c0 + c) * R + r0 + rq * 4;
        *(ushort4*)&oh[o] = vh;
        *(ushort4*)&ol[o] = vl;
    }
}

// circulant taps of the rfft*w->irfft gate (ortho norm, numpy c2r semantics)
__global__ void build_g(const float* __restrict__ cw, float* __restrict__ g)
{
    int d = threadIdx.x;
    if (d >= 64) return;
    float s = cw[0] + ((d & 1) ? -cw[64] : cw[64]);
#pragma unroll
    for (int f = 1; f < 32; ++f) {
        int ph = (f * d) & 63;
        float ang = 6.283185307179586f * (float)ph / 64.0f;
        s += 2.0f * (cw[2 * f] * cosf(ang) + cw[2 * f + 1] * sinf(ang));
    }
    g[d] = s * 0.015625f;   // 1/64
}

// block-diagonal circulant gate matrix GB[768][768], split bf16
// GB[(h,t)][(h2,m)] = (h==h2) ? g[(m-t)&63] : 0
__global__ __launch_bounds__(256)
void build_gb(const float* __restrict__ g, u16* __restrict__ gbh, u16* __restrict__ gbl)
{
    int idx = blockIdx.x * 256 + threadIdx.x;
    if (idx >= Cc * Cc) return;
    int c = idx / Cc, c2 = idx - (idx / Cc) * Cc;
    int h = c >> 6, t = c & 63, h2 = c2 >> 6, m = c2 & 63;
    float v = (h == h2) ? g[(m - t) & 63] : 0.0f;
    u16 hh = f2bf(v);
    gbh[idx] = hh;
    gbl[idx] = f2bf(v - bf2f(hh));
}

// ---------------------------------------------------------------------------
extern "C" void kernel_launch(void* const* d_in, const int* in_sizes, int n_in,
                              void* d_out, int out_size, void* d_ws, size_t ws_size,
                              hipStream_t stream)
{
    (void)in_sizes; (void)n_in; (void)out_size; (void)ws_size;

    const float* x      = (const float*)d_in[0];   // [8,1024,768]
    const float* w_qkv  = (const float*)d_in[1];   // [2304,768]
    const float* w_v1   = (const float*)d_in[2];   // [768,768]
    const float* w_v2   = (const float*)d_in[3];
    const float* w_proj = (const float*)d_in[4];
    const float* b_proj = (const float*)d_in[5];   // [768]
    const float* cw     = (const float*)d_in[6];   // [33,2]

    float* out  = (float*)d_out;                   // [8,1024,768] then attn
    float* attn = out + (long)Bb * Nn * Cc;        // [8,12,1024,1024]

    // ---- workspace layout (bytes) ----
    char* W = (char*)d_ws;
    long off = 0;
    auto alloc = [&](long bytes) { char* p = W + off; off += (bytes + 255) & ~255L; return p; };

    u16*   QKVh  = (u16*)  alloc((long)8192 * 2304 * 2);
    u16*   QKVl  = (u16*)  alloc((long)8192 * 2304 * 2);
    u16*   AHh   = (u16*)  alloc((long)Bb * Nn * Nn * 2);
    u16*   AHl   = (u16*)  alloc((long)Bb * Nn * Nn * 2);
    u16*   VTh   = (u16*)  alloc((long)Bb * Cc * Nn * 2);
    u16*   VTl   = (u16*)  alloc((long)Bb * Cc * Nn * 2);
    u16*   W1Th  = (u16*)  alloc((long)Bb * Cc * Nn * 2);
    u16*   W1Tl  = (u16*)  alloc((long)Bb * Cc * Nn * 2);
    u16*   MVh   = (u16*)  alloc((long)8192 * 768 * 2);
    u16*   MVl   = (u16*)  alloc((long)8192 * 768 * 2);
    u16*   IFVTh = (u16*)  alloc((long)Bb * Cc * Nn * 2);
    u16*   IFVTl = (u16*)  alloc((long)Bb * Cc * Nn * 2);
    u16*   Yh    = (u16*)  alloc((long)8192 * 768 * 2);
    u16*   Yl    = (u16*)  alloc((long)8192 * 768 * 2);
    float* OUTB  = (float*)alloc((long)8192 * 768 * 4);
    u16*   xh    = (u16*)  alloc((long)8192 * 768 * 2);
    u16*   xl    = (u16*)  alloc((long)8192 * 768 * 2);
    u16*   wqh   = (u16*)  alloc((long)2304 * 768 * 2);
    u16*   wql   = (u16*)  alloc((long)2304 * 768 * 2);
    u16*   wv1h  = (u16*)  alloc((long)768 * 768 * 2);
    u16*   wv1l  = (u16*)  alloc((long)768 * 768 * 2);
    u16*   wdh   = (u16*)  alloc((long)768 * 768 * 2);
    u16*   wdl   = (u16*)  alloc((long)768 * 768 * 2);
    u16*   wph   = (u16*)  alloc((long)768 * 768 * 2);
    u16*   wpl   = (u16*)  alloc((long)768 * 768 * 2);
    u16*   gbh   = (u16*)  alloc((long)768 * 768 * 2);
    u16*   gbl   = (u16*)  alloc((long)768 * 768 * 2);
    float* DINV  = (float*)alloc(8192 * 4);
    float* G     = (float*)alloc(256);

    // N x N fp32 scratch for AH lives in the d_out attn region until scores overwrite it
    float* AH = attn;                               // 8 x 1024 x 1024 fp32

    const long sQKV = (long)Nn * LD;                // 2359296 (elems)
    const long sNN  = (long)Nn * Nn;                // 1048576
    const long sNC  = (long)Nn * Cc;                // 786432
    const long sCN  = (long)Cc * Nn;                // 786432 (transposed mats)

    // ---- input splits / small precomputes ----
    build_g<<<1, 64, 0, stream>>>(cw, G);
    build_gb<<<(Cc * Cc + 255) / 256, 256, 0, stream>>>(G, gbh, gbl);
    split_plain<<<2048, 256, 0, stream>>>(x,      xh,   xl,   (long)8192 * 768 / 4);
    split_plain<<<1024, 256, 0, stream>>>(w_qkv,  wqh,  wql,  (long)2304 * 768 / 4);
    split_plain<<<512,  256, 0, stream>>>(w_v1,   wv1h, wv1l, (long)768 * 768 / 4);
    split_plain<<<512,  256, 0, stream>>>(w_proj, wph,  wpl,  (long)768 * 768 / 4);
    wdiff_split<<<512,  256, 0, stream>>>(w_v1, w_v2, wdh, wdl, (long)768 * 768 / 4);

    // 1) QKV = x @ w_qkv^T : split output only
    gemm_ms<128, 128, 32, 2, 2, 0, 1><<<dim3(64, 18, 1), 256, 0, stream>>>(
        xh, xl, nullptr, Cc, 0, 0, wqh, wql, Cc, 0, 0,
        nullptr, QKVh, QKVl, LD, 0, 0, nullptr, nullptr, Cc, 1, 1.0f, 0);

    // 2) AH = Qf @ Kf^T (full channel), fp32 into attn-region scratch
    gemm_ms<64, 64, 64, 2, 2, 0, 0><<<dim3(16, 16, Bb), 256, 0, stream>>>(
        QKVh, QKVl, nullptr, LD, sQKV, 0, QKVh + Cc, QKVl + Cc, LD, sQKV, 0,
        AH, nullptr, nullptr, Nn, sNN, 0, nullptr, nullptr, Cc, 1, 1.0f, 0);

    // 3) symmetrize+relu, degree rsqrt, scale -> split AHn
    sym_relu<<<32768, 256, 0, stream>>>(AH);
    deg_dinv<<<Bb * Nn, 256, 0, stream>>>(AH, DINV);
    scale_split<<<8192, 256, 0, stream>>>(AH, DINV, AHh, AHl);

    // 4) IFVT = GB @ V^T (block-diag circulant gate, transposed split output)
    gemm_ms<64, 64, 64, 2, 2, 0, 1><<<dim3(12, 16, Bb), 256, 0, stream>>>(
        gbh, gbl, nullptr, Cc, 0, 0, QKVh + 2 * Cc, QKVl + 2 * Cc, LD, sQKV, 0,
        nullptr, IFVTh, IFVTl, Nn, sCN, 0, nullptr, nullptr, Cc, 1, 1.0f, 0);

    // 5) VT = split-transpose of V
    t16<<<dim3(16, 12, Bb), 256, 0, stream>>>(
        QKVh + 2 * Cc, QKVl + 2 * Cc, sQKV, LD, VTh, VTl, sCN, Nn);

    // 6) W1T = VT @ AHn^T (AHn symmetric) ; MV = AHn @ W1T^T  => MV = AHn@AHn@V
    gemm_ms<64, 64, 64, 2, 2, 0, 1><<<dim3(12, 16, Bb), 256, 0, stream>>>(
        VTh, VTl, nullptr, Nn, sCN, 0, AHh, AHl, Nn, sNN, 0,
        nullptr, W1Th, W1Tl, Nn, sCN, 0, nullptr, nullptr, Nn, 1, 1.0f, 0);
    gemm_ms<64, 64, 64, 2, 2, 0, 1><<<dim3(16, 12, Bb), 256, 0, stream>>>(
        AHh, AHl, nullptr, Nn, sNN, 0, W1Th, W1Tl, Nn, sCN, 0,
        nullptr, MVh, MVl, Cc, sNC, 0, nullptr, nullptr, Nn, 1, 1.0f, 0);

    // 7) OUTB = -V @ w_v1^T + MV @ (w_v1-w_v2)^T
    gemm_ms<64, 64, 64, 2, 2, 0, 0><<<dim3(128, 12, 1), 256, 0, stream>>>(
        QKVh + 2 * Cc, QKVl + 2 * Cc, nullptr, LD, 0, 0, wv1h, wv1l, Cc, 0, 0,
        OUTB, nullptr, nullptr, Cc, 0, 0, nullptr, nullptr, Cc, 1, -1.0f, 0);
    gemm_ms<64, 64, 64, 2, 2, 0, 0><<<dim3(128, 12, 1), 256, 0, stream>>>(
        MVh, MVl, nullptr, Cc, 0, 0, wdh, wdl, Cc, 0, 0,
        OUTB, nullptr, nullptr, Cc, 0, 0, nullptr, nullptr, Cc, 1, 1.0f, 1);

    // 8) per-head scaled scores -> attn (overwrites AH scratch; AH dead)
    gemm_ms<128, 128, 32, 2, 2, 0, 0><<<dim3(8, 8, Bb * Hh), 256, 0, stream>>>(
        QKVh, QKVl, nullptr, LD, sQKV, HD, QKVh + Cc, QKVl + Cc, LD, sQKV, HD,
        attn, nullptr, nullptr, Nn, (long)Hh * sNN, sNN,
        nullptr, nullptr, HD, Hh, 0.125f, 0);

    // 9) softmax rows in-place
    softmax_rows<<<Bb * Hh * Nn, 256, 0, stream>>>(attn);

    // 10) Y = attn @ IFV per head (A = fp32 attn converted in staging; B = IFVT)
    gemm_ms<64, 64, 64, 2, 2, 1, 1><<<dim3(16, 1, Bb * Hh), 256, 0, stream>>>(
        nullptr, nullptr, attn, Nn, (long)Hh * sNN, sNN,
        IFVTh, IFVTl, Nn, sCN, (long)HD * Nn,
        nullptr, Yh, Yl, Cc, sNC, HD, nullptr, nullptr, Nn, Hh, 1.0f, 0);

    // 11) out = Y @ w_proj^T + b_proj + OUTB
    gemm_ms<64, 64, 64, 2, 2, 0, 0><<<dim3(128, 12, 1), 256, 0, stream>>>(
        Yh, Yl, nullptr, Cc, 0, 0, wph, wpl, Cc, 0, 0,
        out, nullptr, nullptr, Cc, 0, 0, OUTB, b_proj, Cc, 1, 1.0f, 0);
}